// Round 8
// baseline (80.165 us; speedup 1.0000x reference)
//
#include <hip/hip_runtime.h>

#define BB 2
#define TT 512
#define HH 256
#define NBT (BB * TT)

#define C2LOG2E 2.8853900817779268f   // 2*log2(e): exp(2x)=2^(C*x)
#define LOG2E   1.4426950408889634f

__device__ __forceinline__ unsigned short f2bf(float f) {   // RNE float->bf16
    unsigned u = __float_as_uint(f);
    unsigned r = u + 0x7fffu + ((u >> 16) & 1u);
    return (unsigned short)(r >> 16);
}
__device__ __forceinline__ float bflo(unsigned u) { return __uint_as_float(u << 16); }
__device__ __forceinline__ float bfhi(unsigned u) { return __uint_as_float(u & 0xffff0000u); }

// ---------------------------------------------------------------------------
// Kernel 1 (proj_all), grid 1280 x 256:
//   blocks [0,512):    Q-proj -> Eq fp32 [bt][h]      (round-4 structure)
//   blocks [512,1024): K-proj -> EkT16 bf16 [h8][bt][8] via LDS bounce
//   blocks [1024,1280): K -> K16 bf16 convert
// Proj block = 8 rows x 64 outs; thread (o = tid&63, rs = tid>>6) does 2 rows.
// W loads: lane o reads row-major W[o0+o][h] float4 (L2-resident).
// X loads: wave-uniform (scalar path).
// ---------------------------------------------------------------------------
__global__ __launch_bounds__(256) void proj_all_kernel(
    const float* __restrict__ Q, const float* __restrict__ K,
    const float* __restrict__ Wq, const float* __restrict__ Wk,
    float* __restrict__ Eq, unsigned short* __restrict__ EkT16,
    unsigned short* __restrict__ K16)
{
    int bid = blockIdx.x;
    int tid = threadIdx.x;

    if (bid >= 1024) {   // ---- K -> bf16 convert ----
        int i = (bid - 1024) * 1024 + tid * 4;     // NBT*HH = 262144 elems
        float4 k4 = *reinterpret_cast<const float4*>(K + i);
        ushort4 o4;
        o4.x = f2bf(k4.x); o4.y = f2bf(k4.y); o4.z = f2bf(k4.z); o4.w = f2bf(k4.w);
        *reinterpret_cast<ushort4*>(K16 + i) = o4;
        return;
    }

    bool isK = (bid >= 512);
    int g = isK ? bid - 512 : bid;
    int rowgrp = g >> 2;            // 0..127
    int ogrp = g & 3;               // 0..3
    int bt0 = rowgrp * 8;
    int o0 = ogrp * 64;

    const float* X = isK ? K : Q;
    const float* W = isK ? Wk : Wq;

    int o  = tid & 63;
    int rs = tid >> 6;              // 0..3 (wave)
    int r0 = bt0 + rs * 2;

    const float4* w4p  = reinterpret_cast<const float4*>(W + (o0 + o) * HH);
    const float4* x4p0 = reinterpret_cast<const float4*>(X + r0 * HH);
    const float4* x4p1 = reinterpret_cast<const float4*>(X + (r0 + 1) * HH);

    float acc0 = 0.f, acc1 = 0.f;
#pragma unroll 4
    for (int h4 = 0; h4 < HH / 4; ++h4) {
        float4 w4 = w4p[h4];
        float4 xa = x4p0[h4];       // wave-uniform address
        float4 xb = x4p1[h4];       // wave-uniform address
        acc0 += xa.x * w4.x + xa.y * w4.y + xa.z * w4.z + xa.w * w4.w;
        acc1 += xb.x * w4.x + xb.y * w4.y + xb.z * w4.z + xb.w * w4.w;
    }
    float e0 = __builtin_amdgcn_exp2f(acc0 * C2LOG2E);
    float e1 = __builtin_amdgcn_exp2f(acc1 * C2LOG2E);

    if (!isK) {
        Eq[r0 * HH + o0 + o]       = e0;           // coalesced 256B/wave
        Eq[(r0 + 1) * HH + o0 + o] = e1;
    } else {
        __shared__ unsigned short ek_sh[8][64];
        ek_sh[rs * 2][o]     = f2bf(e0);
        ek_sh[rs * 2 + 1][o] = f2bf(e1);
        __syncthreads();
        // 64 writer threads: thread w = ls*8 + r moves 8 bf16 (16B)
        // to EkT16[((o0>>3)+ls)*NBT + bt0 + r][0..8)
        if (tid < 64) {
            int ls = tid >> 3, r = tid & 7;
            uint4 val = *reinterpret_cast<const uint4*>(&ek_sh[r][ls * 8]);
            *reinterpret_cast<uint4*>(
                EkT16 + (((o0 >> 3) + ls) * NBT + bt0 + r) * 8) = val;
        }
    }
}

// ---------------------------------------------------------------------------
// Kernel 2 (attn): scores (bf16 EkT) + softmax (no max-sub; scores bounded
// by 2*sum|v| ~ 26, exp2 safe in fp32) + context (bf16 K).
// One block per (b,t), 512 threads; block->t permuted for load balance.
// ---------------------------------------------------------------------------
__global__ __launch_bounds__(512, 8) void attn_kernel(
    const float* __restrict__ Eq, const unsigned short* __restrict__ EkT16,
    const unsigned short* __restrict__ K16, const float* __restrict__ v,
    float* __restrict__ ctx, float* __restrict__ alpha)
{
    __shared__ float eq_sh[HH];
    __shared__ float v2_sh[HH];
    __shared__ float al_sh[TT];
    __shared__ float red[8];
    __shared__ float4 cred[8][64];

    int bt = blockIdx.x;
    int b = bt / TT;
    int idx = bt % TT;
    int t = (idx < 256) ? idx : 767 - idx;
    int btr = b * TT + t;
    int tid = threadIdx.x;

    if (tid < HH) {
        eq_sh[tid] = Eq[btr * HH + tid];
        v2_sh[tid] = -2.0f * v[tid];
    }
    __syncthreads();

    // ---- score for s = tid ----
    float sc = 0.f;
    if (tid <= t) {
        const uint4* ek = reinterpret_cast<const uint4*>(EkT16) + (b * TT + tid);
        const float4* q4p = reinterpret_cast<const float4*>(eq_sh);
        const float4* v4p = reinterpret_cast<const float4*>(v2_sh);
#pragma unroll 2
        for (int h8 = 0; h8 < 32; ++h8) {
            uint4 kk = ek[h8 * NBT];             // lanes contiguous: 1KB/wave
            float4 qa = q4p[2 * h8], qb = q4p[2 * h8 + 1];
            float4 va = v4p[2 * h8], vb = v4p[2 * h8 + 1];
            float r0 = __builtin_amdgcn_rcpf(__builtin_fmaf(qa.x, bflo(kk.x), 1.f));
            float r1 = __builtin_amdgcn_rcpf(__builtin_fmaf(qa.y, bfhi(kk.x), 1.f));
            float r2 = __builtin_amdgcn_rcpf(__builtin_fmaf(qa.z, bflo(kk.y), 1.f));
            float r3 = __builtin_amdgcn_rcpf(__builtin_fmaf(qa.w, bfhi(kk.y), 1.f));
            float r4 = __builtin_amdgcn_rcpf(__builtin_fmaf(qb.x, bflo(kk.z), 1.f));
            float r5 = __builtin_amdgcn_rcpf(__builtin_fmaf(qb.y, bfhi(kk.z), 1.f));
            float r6 = __builtin_amdgcn_rcpf(__builtin_fmaf(qb.z, bflo(kk.w), 1.f));
            float r7 = __builtin_amdgcn_rcpf(__builtin_fmaf(qb.w, bfhi(kk.w), 1.f));
            sc = __builtin_fmaf(va.x, r0, sc);
            sc = __builtin_fmaf(va.y, r1, sc);
            sc = __builtin_fmaf(va.z, r2, sc);
            sc = __builtin_fmaf(va.w, r3, sc);
            sc = __builtin_fmaf(vb.x, r4, sc);
            sc = __builtin_fmaf(vb.y, r5, sc);
            sc = __builtin_fmaf(vb.z, r6, sc);
            sc = __builtin_fmaf(vb.w, r7, sc);
        }
    }

    // ---- softmax: sum only (scores bounded, no max-sub needed) ----
    float e = (tid <= t) ? __builtin_amdgcn_exp2f(sc * LOG2E) : 0.f;
    float ssum = e;
#pragma unroll
    for (int off = 32; off > 0; off >>= 1)
        ssum += __shfl_xor(ssum, off);
    if ((tid & 63) == 0) red[tid >> 6] = ssum;
    __syncthreads();
    float denom = (red[0] + red[1]) + (red[2] + red[3])
                + (red[4] + red[5]) + (red[6] + red[7]);
    float a0 = e * __builtin_amdgcn_rcpf(denom);

    al_sh[tid] = a0;
    alpha[btr * TT + tid] = a0;
    __syncthreads();

    // ---- context: hc = tid&63 (4 channels), sg = tid>>6 (s-stride 8) ----
    int hc = tid & 63, sg = tid >> 6;
    const uint2* kb = reinterpret_cast<const uint2*>(K16 + b * TT * HH);
    float4 acc4 = {0.f, 0.f, 0.f, 0.f};
    for (int s = sg; s <= t; s += 8) {
        uint2 kk = kb[s * 64 + hc];              // 8B/lane, coalesced
        float al = al_sh[s];                     // wave-uniform broadcast
        acc4.x = __builtin_fmaf(al, bflo(kk.x), acc4.x);
        acc4.y = __builtin_fmaf(al, bfhi(kk.x), acc4.y);
        acc4.z = __builtin_fmaf(al, bflo(kk.y), acc4.z);
        acc4.w = __builtin_fmaf(al, bfhi(kk.y), acc4.w);
    }
    cred[sg][hc] = acc4;
    __syncthreads();
    if (sg == 0) {
        float4 out = {0.f, 0.f, 0.f, 0.f};
#pragma unroll
        for (int g = 0; g < 8; ++g) {
            float4 c = cred[g][hc];
            out.x += c.x; out.y += c.y; out.z += c.z; out.w += c.w;
        }
        reinterpret_cast<float4*>(ctx + btr * HH)[hc] = out;
    }
}

extern "C" void kernel_launch(void* const* d_in, const int* in_sizes, int n_in,
                              void* d_out, int out_size, void* d_ws, size_t ws_size,
                              hipStream_t stream) {
    const float* Q  = (const float*)d_in[0];
    const float* K  = (const float*)d_in[1];
    const float* Wq = (const float*)d_in[2];
    const float* Wk = (const float*)d_in[3];
    const float* v  = (const float*)d_in[4];

    float* ctx   = (float*)d_out;                      // B*T*H
    float* alpha = (float*)d_out + NBT * HH;           // B*T*T

    // workspace layout: Eq fp32 | K16 bf16 | EkT16 bf16
    float* Eq = (float*)d_ws;                                  // NBT*HH fp32
    unsigned short* K16   = (unsigned short*)(Eq + NBT * HH);  // NBT*HH bf16
    unsigned short* EkT16 = K16 + NBT * HH;                    // NBT*HH bf16

    proj_all_kernel<<<1280, 256, 0, stream>>>(Q, K, Wq, Wk, Eq, EkT16, K16);
    attn_kernel<<<NBT, 512, 0, stream>>>(Eq, EkT16, K16, v, ctx, alpha);
}

// Round 9
// 47.269 us; speedup vs baseline: 1.6959x; 1.6959x over previous
//
#include <hip/hip_runtime.h>

#define BB 2
#define TT 512
#define HH 256
#define NBT (BB * TT)

#define C2LOG2E 2.8853900817779268f   // 2*log2(e): exp(2x)=2^(C*x)
#define LOG2E   1.4426950408889634f

// ---------------------------------------------------------------------------
// Kernel 1 (proj): Y = exp2(C * X @ W^T), LDS-staged GEMM.
// Grid 256: bid>>7 = mat (0:Q->Eq, 1:K->EkT), (bid&127)*8 = row block.
// Per ko-tile (BK=64): stage W[0..256)[ko*64..+64) into w_sh coalesced
// (wave reads 4 contiguous 256B rows per instr), then thread tid=o computes
// 8 rows from LDS. X loads are wave-uniform (compiler can scalarize).
// Q-half writes Eq[bt][o] coalesced. K-half transposes via LDS bounce to
// EkT fp32 [h4][bt][4] so attn's thread=s loads are lane-contiguous.
// ---------------------------------------------------------------------------
__global__ __launch_bounds__(256) void proj_kernel(
    const float* __restrict__ Q, const float* __restrict__ K,
    const float* __restrict__ Wq, const float* __restrict__ Wk,
    float* __restrict__ Eq, float* __restrict__ EkT)
{
    __shared__ float w_sh[256][68];     // 68-pad: f4 reads bank-balanced

    int bid = blockIdx.x;
    int tid = threadIdx.x;              // = output channel o
    bool isK = (bid >= 128);
    int bt0 = (bid & 127) * 8;
    const float* X = isK ? K : Q;
    const float* W = isK ? Wk : Wq;

    float acc[8] = {0.f, 0.f, 0.f, 0.f, 0.f, 0.f, 0.f, 0.f};

    for (int ko = 0; ko < 4; ++ko) {
        // ---- stage W tile (256 o x 64 h), coalesced ----
        __syncthreads();                // previous tile fully consumed
#pragma unroll
        for (int p = 0; p < 16; ++p) {
            int idx = p * 256 + tid;
            int orow = idx >> 4, c = idx & 15;
            *reinterpret_cast<float4*>(&w_sh[orow][c * 4]) =
                *reinterpret_cast<const float4*>(W + orow * HH + ko * 64 + c * 4);
        }
        __syncthreads();

        // ---- compute: 8 rows, h4-outer so w4 is reused across rows ----
#pragma unroll 4
        for (int h4 = 0; h4 < 16; ++h4) {
            float4 w4 = *reinterpret_cast<const float4*>(&w_sh[tid][h4 * 4]);
#pragma unroll
            for (int r = 0; r < 8; ++r) {
                float4 x4 = *reinterpret_cast<const float4*>(
                    X + (bt0 + r) * HH + ko * 64 + h4 * 4);   // wave-uniform
                float a = acc[r];
                a = __builtin_fmaf(x4.x, w4.x, a);
                a = __builtin_fmaf(x4.y, w4.y, a);
                a = __builtin_fmaf(x4.z, w4.z, a);
                a = __builtin_fmaf(x4.w, w4.w, a);
                acc[r] = a;
            }
        }
    }

    float e[8];
#pragma unroll
    for (int r = 0; r < 8; ++r)
        e[r] = __builtin_amdgcn_exp2f(acc[r] * C2LOG2E);

    if (!isK) {
#pragma unroll
        for (int r = 0; r < 8; ++r)
            Eq[(bt0 + r) * HH + tid] = e[r];     // lanes o -> coalesced
    } else {
        // transpose bounce: ek[r][o] in LDS (reuse w_sh), then write
        // EkT f4-slot (h4*NBT + bt0 + r) with r-fast lanes (contiguous).
        float* ek = &w_sh[0][0];                 // 8*256 floats = 8KB
        __syncthreads();                         // done with w_sh as W
#pragma unroll
        for (int r = 0; r < 8; ++r)
            ek[r * 256 + tid] = e[r];
        __syncthreads();
#pragma unroll
        for (int p = 0; p < 2; ++p) {
            int idx = p * 256 + tid;             // 512 f4 moves
            int r = idx & 7, h4 = idx >> 3;
            float4 val = *reinterpret_cast<const float4*>(&ek[r * 256 + h4 * 4]);
            *reinterpret_cast<float4*>(EkT + (h4 * NBT + bt0 + r) * 4) = val;
        }
    }
}

// ---------------------------------------------------------------------------
// Kernel 2 (attn): round-5 structure (fp32, measured ~21us) minus max-sub
// (scores bounded by 2*sum|v| ~ 26 -> exp2 safe in fp32).
// One block per (b,t), 512 threads; block->t permuted for load balance.
// score'(t,s) = sum_h v2[h] * rcp(Eq[t,h]*Ek[s,h] + 1),  v2 = -2v
// ---------------------------------------------------------------------------
__global__ __launch_bounds__(512, 8) void attn_kernel(
    const float* __restrict__ Eq, const float* __restrict__ EkT,
    const float* __restrict__ Kraw, const float* __restrict__ v,
    float* __restrict__ ctx, float* __restrict__ alpha)
{
    __shared__ float eq_sh[HH];
    __shared__ float v2_sh[HH];
    __shared__ float al_sh[TT];
    __shared__ float red[8];
    __shared__ float4 cred[8][64];

    int bt = blockIdx.x;
    int b = bt / TT;
    int idx = bt % TT;
    int t = (idx < 256) ? idx : 767 - idx;
    int btr = b * TT + t;
    int tid = threadIdx.x;

    if (tid < HH) {
        eq_sh[tid] = Eq[btr * HH + tid];
        v2_sh[tid] = -2.0f * v[tid];
    }
    __syncthreads();

    // ---- score for s = tid (coalesced EkT loads: lanes contiguous) ----
    float sc = 0.f;
    if (tid <= t) {
        const float4* ek = reinterpret_cast<const float4*>(EkT) + (b * TT + tid);
        const float4* q4p = reinterpret_cast<const float4*>(eq_sh);
        const float4* v4p = reinterpret_cast<const float4*>(v2_sh);
#pragma unroll 4
        for (int h4 = 0; h4 < HH / 4; ++h4) {
            float4 e4 = ek[h4 * NBT];     // 1KB/wave
            float4 q4 = q4p[h4];          // broadcast
            float4 vv = v4p[h4];          // broadcast
            float r0 = __builtin_amdgcn_rcpf(__builtin_fmaf(q4.x, e4.x, 1.f));
            float r1 = __builtin_amdgcn_rcpf(__builtin_fmaf(q4.y, e4.y, 1.f));
            float r2 = __builtin_amdgcn_rcpf(__builtin_fmaf(q4.z, e4.z, 1.f));
            float r3 = __builtin_amdgcn_rcpf(__builtin_fmaf(q4.w, e4.w, 1.f));
            sc = __builtin_fmaf(vv.x, r0, sc);
            sc = __builtin_fmaf(vv.y, r1, sc);
            sc = __builtin_fmaf(vv.z, r2, sc);
            sc = __builtin_fmaf(vv.w, r3, sc);
        }
    }

    // ---- softmax: sum only ----
    float e = (tid <= t) ? __builtin_amdgcn_exp2f(sc * LOG2E) : 0.f;
    float ssum = e;
#pragma unroll
    for (int off = 32; off > 0; off >>= 1)
        ssum += __shfl_xor(ssum, off);
    if ((tid & 63) == 0) red[tid >> 6] = ssum;
    __syncthreads();
    float denom = (red[0] + red[1]) + (red[2] + red[3])
                + (red[4] + red[5]) + (red[6] + red[7]);
    float a0 = e * __builtin_amdgcn_rcpf(denom);

    al_sh[tid] = a0;
    alpha[btr * TT + tid] = a0;
    __syncthreads();

    // ---- context: hc = tid&63 (4 channels), sg = tid>>6 (s-stride 8) ----
    int hc = tid & 63, sg = tid >> 6;
    const float4* kb4 = reinterpret_cast<const float4*>(Kraw + b * TT * HH) + hc;
    float4 acc4 = {0.f, 0.f, 0.f, 0.f};
    for (int s = sg; s <= t; s += 8) {
        float4 k4 = kb4[s * 64];             // coalesced 1KB/wave
        float  al = al_sh[s];                // wave-uniform broadcast
        acc4.x = __builtin_fmaf(al, k4.x, acc4.x);
        acc4.y = __builtin_fmaf(al, k4.y, acc4.y);
        acc4.z = __builtin_fmaf(al, k4.z, acc4.z);
        acc4.w = __builtin_fmaf(al, k4.w, acc4.w);
    }
    cred[sg][hc] = acc4;
    __syncthreads();
    if (sg == 0) {
        float4 out = {0.f, 0.f, 0.f, 0.f};
#pragma unroll
        for (int g = 0; g < 8; ++g) {
            float4 c = cred[g][hc];
            out.x += c.x; out.y += c.y; out.z += c.z; out.w += c.w;
        }
        reinterpret_cast<float4*>(ctx + btr * HH)[hc] = out;
    }
}

extern "C" void kernel_launch(void* const* d_in, const int* in_sizes, int n_in,
                              void* d_out, int out_size, void* d_ws, size_t ws_size,
                              hipStream_t stream) {
    const float* Q  = (const float*)d_in[0];
    const float* K  = (const float*)d_in[1];
    const float* Wq = (const float*)d_in[2];
    const float* Wk = (const float*)d_in[3];
    const float* v  = (const float*)d_in[4];

    float* ctx   = (float*)d_out;                      // B*T*H
    float* alpha = (float*)d_out + NBT * HH;           // B*T*T

    float* Eq  = (float*)d_ws;                         // NBT*HH fp32
    float* EkT = Eq + NBT * HH;                        // NBT*HH fp32, [h4][bt][4]

    proj_kernel<<<256, 256, 0, stream>>>(Q, K, Wq, Wk, Eq, EkT);
    attn_kernel<<<NBT, 512, 0, stream>>>(Eq, EkT, K, v, ctx, alpha);
}

// Round 10
// 39.655 us; speedup vs baseline: 2.0216x; 1.1920x over previous
//
#include <hip/hip_runtime.h>

#define BB 2
#define TT 512
#define HH 256
#define NBT (BB * TT)          // 1024

#define C2LOG2E 2.8853900817779268f   // 2*log2(e): exp(2x)=2^(C*x)
#define LOG2E   1.4426950408889634f

typedef __attribute__((ext_vector_type(8))) short short8;
typedef __attribute__((ext_vector_type(4))) float f32x4;

__device__ __forceinline__ unsigned short f2bf(float f) {   // RNE float->bf16
    unsigned u = __float_as_uint(f);
    unsigned r = u + 0x7fffu + ((u >> 16) & 1u);
    return (unsigned short)(r >> 16);
}

// ---------------------------------------------------------------------------
// Kernel 0 (prep): convert Q,K,Wq,Wk -> contiguous bf16 buffers.
// grid 640: [0,256) Q, [256,512) K, [512,576) Wq, [576,640) Wk.
// ---------------------------------------------------------------------------
__global__ __launch_bounds__(256) void prep_kernel(
    const float* __restrict__ Q, const float* __restrict__ K,
    const float* __restrict__ Wq, const float* __restrict__ Wk,
    unsigned short* __restrict__ Qb, unsigned short* __restrict__ Kb,
    unsigned short* __restrict__ Wqb, unsigned short* __restrict__ Wkb)
{
    int bid = blockIdx.x, tid = threadIdx.x;
    const float* src;
    unsigned short* dst;
    int base;
    if (bid < 256)      { src = Q;  dst = Qb;  base = bid * 1024; }
    else if (bid < 512) { src = K;  dst = Kb;  base = (bid - 256) * 1024; }
    else if (bid < 576) { src = Wq; dst = Wqb; base = (bid - 512) * 1024; }
    else                { src = Wk; dst = Wkb; base = (bid - 576) * 1024; }
    int i = base + tid * 4;
    float4 x4 = *reinterpret_cast<const float4*>(src + i);
    ushort4 o4;
    o4.x = f2bf(x4.x); o4.y = f2bf(x4.y); o4.z = f2bf(x4.z); o4.w = f2bf(x4.w);
    *reinterpret_cast<ushort4*>(dst + i) = o4;
}

// ---------------------------------------------------------------------------
// Kernel 1 (proj_mfma): [2048 x 256] = X[2048 x 256] @ W^T via
// mfma_f32_16x16x32_bf16. One 32x32 output tile per wave; 512 waves total
// (grid 128 x 256thr). Fragments loaded directly from global (L2-resident).
// A-frag lane l: X[bt0 + mi*16 + (l&15)][kb*32 + (l>>4)*8 + j]
// B-frag lane l: W[o0 + ni*16 + (l&15)][kb*32 + (l>>4)*8 + j]  (B=W^T)
// C/D lane l reg j: row = (l>>4)*4 + j, col = l&15   [m89-verified]
// Epilogue: e = exp2(C * acc); Q-half -> Eq[bt][o] fp32;
// K-half -> EkT fp32 [h4][bt][4] (attn's coalesced layout).
// ---------------------------------------------------------------------------
__global__ __launch_bounds__(256) void proj_mfma_kernel(
    const unsigned short* __restrict__ Qb, const unsigned short* __restrict__ Kb,
    const unsigned short* __restrict__ Wqb, const unsigned short* __restrict__ Wkb,
    float* __restrict__ Eq, float* __restrict__ EkT)
{
    int wid_g = blockIdx.x * 4 + (threadIdx.x >> 6);   // 0..511
    int lane = threadIdx.x & 63;
    int btile = wid_g >> 3;          // 0..63  (x32 rows)
    int otile = wid_g & 7;           // 0..7   (x32 outs)
    bool isK = (btile >= 32);
    int bt0 = (btile & 31) * 32;
    int o0 = otile * 32;
    const unsigned short* X = isK ? Kb : Qb;
    const unsigned short* W = isK ? Wkb : Wqb;

    int rsel = lane & 15;            // row-within-16 for A/B frags
    int ksel = (lane >> 4) * 8;      // k-offset within 32

    f32x4 c00 = {0.f,0.f,0.f,0.f}, c01 = {0.f,0.f,0.f,0.f};
    f32x4 c10 = {0.f,0.f,0.f,0.f}, c11 = {0.f,0.f,0.f,0.f};

#pragma unroll
    for (int kb = 0; kb < 8; ++kb) {
        int ko = kb * 32 + ksel;
        short8 a0 = *reinterpret_cast<const short8*>(X + (bt0 + rsel) * HH + ko);
        short8 a1 = *reinterpret_cast<const short8*>(X + (bt0 + 16 + rsel) * HH + ko);
        short8 b0 = *reinterpret_cast<const short8*>(W + (o0 + rsel) * HH + ko);
        short8 b1 = *reinterpret_cast<const short8*>(W + (o0 + 16 + rsel) * HH + ko);
        c00 = __builtin_amdgcn_mfma_f32_16x16x32_bf16(a0, b0, c00, 0, 0, 0);
        c01 = __builtin_amdgcn_mfma_f32_16x16x32_bf16(a0, b1, c01, 0, 0, 0);
        c10 = __builtin_amdgcn_mfma_f32_16x16x32_bf16(a1, b0, c10, 0, 0, 0);
        c11 = __builtin_amdgcn_mfma_f32_16x16x32_bf16(a1, b1, c11, 0, 0, 0);
    }

    int rbase = (lane >> 4) * 4;     // C/D row base
    int cbase = lane & 15;           // C/D col
#pragma unroll
    for (int mi = 0; mi < 2; ++mi) {
#pragma unroll
        for (int ni = 0; ni < 2; ++ni) {
            f32x4 cc = (mi == 0) ? (ni == 0 ? c00 : c01)
                                 : (ni == 0 ? c10 : c11);
#pragma unroll
            for (int j = 0; j < 4; ++j) {
                float e = __builtin_amdgcn_exp2f(cc[j] * C2LOG2E);
                int r = bt0 + mi * 16 + rbase + j;     // bt row (0..1023)
                int o = o0 + ni * 16 + cbase;          // out channel
                if (!isK)
                    Eq[r * HH + o] = e;
                else
                    EkT[((o >> 2) * NBT + r) * 4 + (o & 3)] = e;
            }
        }
    }
}

// ---------------------------------------------------------------------------
// Kernel 2 (attn): unchanged from round 8 (measured ~5us).
// scores via rcp(Eq*Ek+1) + sum-only softmax + fp32 K context.
// ---------------------------------------------------------------------------
__global__ __launch_bounds__(512, 8) void attn_kernel(
    const float* __restrict__ Eq, const float* __restrict__ EkT,
    const float* __restrict__ Kraw, const float* __restrict__ v,
    float* __restrict__ ctx, float* __restrict__ alpha)
{
    __shared__ float eq_sh[HH];
    __shared__ float v2_sh[HH];
    __shared__ float al_sh[TT];
    __shared__ float red[8];
    __shared__ float4 cred[8][64];

    int bt = blockIdx.x;
    int b = bt / TT;
    int idx = bt % TT;
    int t = (idx < 256) ? idx : 767 - idx;
    int btr = b * TT + t;
    int tid = threadIdx.x;

    if (tid < HH) {
        eq_sh[tid] = Eq[btr * HH + tid];
        v2_sh[tid] = -2.0f * v[tid];
    }
    __syncthreads();

    // ---- score for s = tid (coalesced EkT loads: lanes contiguous) ----
    float sc = 0.f;
    if (tid <= t) {
        const float4* ek = reinterpret_cast<const float4*>(EkT) + (b * TT + tid);
        const float4* q4p = reinterpret_cast<const float4*>(eq_sh);
        const float4* v4p = reinterpret_cast<const float4*>(v2_sh);
#pragma unroll 4
        for (int h4 = 0; h4 < HH / 4; ++h4) {
            float4 e4 = ek[h4 * NBT];     // 1KB/wave
            float4 q4 = q4p[h4];          // broadcast
            float4 vv = v4p[h4];          // broadcast
            float r0 = __builtin_amdgcn_rcpf(__builtin_fmaf(q4.x, e4.x, 1.f));
            float r1 = __builtin_amdgcn_rcpf(__builtin_fmaf(q4.y, e4.y, 1.f));
            float r2 = __builtin_amdgcn_rcpf(__builtin_fmaf(q4.z, e4.z, 1.f));
            float r3 = __builtin_amdgcn_rcpf(__builtin_fmaf(q4.w, e4.w, 1.f));
            sc = __builtin_fmaf(vv.x, r0, sc);
            sc = __builtin_fmaf(vv.y, r1, sc);
            sc = __builtin_fmaf(vv.z, r2, sc);
            sc = __builtin_fmaf(vv.w, r3, sc);
        }
    }

    // ---- softmax: sum only (scores bounded by 2*sum|v| ~ 26) ----
    float e = (tid <= t) ? __builtin_amdgcn_exp2f(sc * LOG2E) : 0.f;
    float ssum = e;
#pragma unroll
    for (int off = 32; off > 0; off >>= 1)
        ssum += __shfl_xor(ssum, off);
    if ((tid & 63) == 0) red[tid >> 6] = ssum;
    __syncthreads();
    float denom = (red[0] + red[1]) + (red[2] + red[3])
                + (red[4] + red[5]) + (red[6] + red[7]);
    float a0 = e * __builtin_amdgcn_rcpf(denom);

    al_sh[tid] = a0;
    alpha[btr * TT + tid] = a0;
    __syncthreads();

    // ---- context: hc = tid&63 (4 channels), sg = tid>>6 (s-stride 8) ----
    int hc = tid & 63, sg = tid >> 6;
    const float4* kb4 = reinterpret_cast<const float4*>(Kraw + b * TT * HH) + hc;
    float4 acc4 = {0.f, 0.f, 0.f, 0.f};
    for (int s = sg; s <= t; s += 8) {
        float4 k4 = kb4[s * 64];             // coalesced 1KB/wave
        float  al = al_sh[s];                // wave-uniform broadcast
        acc4.x = __builtin_fmaf(al, k4.x, acc4.x);
        acc4.y = __builtin_fmaf(al, k4.y, acc4.y);
        acc4.z = __builtin_fmaf(al, k4.z, acc4.z);
        acc4.w = __builtin_fmaf(al, k4.w, acc4.w);
    }
    cred[sg][hc] = acc4;
    __syncthreads();
    if (sg == 0) {
        float4 out = {0.f, 0.f, 0.f, 0.f};
#pragma unroll
        for (int g = 0; g < 8; ++g) {
            float4 cc = cred[g][hc];
            out.x += cc.x; out.y += cc.y; out.z += cc.z; out.w += cc.w;
        }
        reinterpret_cast<float4*>(ctx + btr * HH)[hc] = out;
    }
}

extern "C" void kernel_launch(void* const* d_in, const int* in_sizes, int n_in,
                              void* d_out, int out_size, void* d_ws, size_t ws_size,
                              hipStream_t stream) {
    const float* Q  = (const float*)d_in[0];
    const float* K  = (const float*)d_in[1];
    const float* Wq = (const float*)d_in[2];
    const float* Wk = (const float*)d_in[3];
    const float* v  = (const float*)d_in[4];

    float* ctx   = (float*)d_out;                      // B*T*H
    float* alpha = (float*)d_out + NBT * HH;           // B*T*T

    // ws: Eq fp32 | EkT fp32 | Qb | Kb | Wqb | Wkb  (bf16)
    float* Eq  = (float*)d_ws;                         // NBT*HH fp32 (1 MB)
    float* EkT = Eq + NBT * HH;                        // NBT*HH fp32 (1 MB)
    unsigned short* Qb  = (unsigned short*)(EkT + NBT * HH);   // 512 KB
    unsigned short* Kb  = Qb + NBT * HH;                       // 512 KB
    unsigned short* Wqb = Kb + NBT * HH;                       // 128 KB
    unsigned short* Wkb = Wqb + HH * HH;                       // 128 KB

    prep_kernel<<<640, 256, 0, stream>>>(Q, K, Wq, Wk, Qb, Kb, Wqb, Wkb);
    proj_mfma_kernel<<<128, 256, 0, stream>>>(Qb, Kb, Wqb, Wkb, Eq, EkT);
    attn_kernel<<<NBT, 512, 0, stream>>>(Eq, EkT, K, v, ctx, alpha);
}

// Round 11
// 37.512 us; speedup vs baseline: 2.1371x; 1.0571x over previous
//
#include <hip/hip_runtime.h>

#define BB 2
#define TT 512
#define HH 256
#define NBT (BB * TT)          // 1024

#define C2LOG2E 2.8853900817779268f   // 2*log2(e): exp(2x)=2^(C*x)
#define LOG2E   1.4426950408889634f

typedef __attribute__((ext_vector_type(8))) short short8;
typedef __attribute__((ext_vector_type(4))) float f32x4;

__device__ __forceinline__ unsigned short f2bf(float f) {   // RNE float->bf16
    unsigned u = __float_as_uint(f);
    unsigned r = u + 0x7fffu + ((u >> 16) & 1u);
    return (unsigned short)(r >> 16);
}

// load 8 consecutive fp32 and convert to a bf16 MFMA fragment
__device__ __forceinline__ short8 load_cvt8(const float* __restrict__ p) {
    float4 x0 = *reinterpret_cast<const float4*>(p);
    float4 x1 = *reinterpret_cast<const float4*>(p + 4);
    short8 r;
    r[0] = (short)f2bf(x0.x); r[1] = (short)f2bf(x0.y);
    r[2] = (short)f2bf(x0.z); r[3] = (short)f2bf(x0.w);
    r[4] = (short)f2bf(x1.x); r[5] = (short)f2bf(x1.y);
    r[6] = (short)f2bf(x1.z); r[7] = (short)f2bf(x1.w);
    return r;
}

// ---------------------------------------------------------------------------
// Kernel 1 (proj_mfma): [2048 x 256] = X[2048 x 256] @ W^T via
// mfma_f32_16x16x32_bf16, fp32 inputs converted in-register.
// One 16x16 output tile per wave; 2048 waves (grid 512 x 256thr,
// 8 waves/CU). #pragma unroll 2 keeps in-flight loads bounded (no spill).
// A-frag lane l: X[bt0 + (l&15)][kb*32 + (l>>4)*8 + j]
// B-frag lane l: W[o0  + (l&15)][kb*32 + (l>>4)*8 + j]   (B = W^T)
// C/D lane l reg j: row = (l>>4)*4 + j, col = l&15   [m89-verified]
// Epilogue: e = exp2(C*acc); Q-half -> Eq[bt][o] fp32;
// K-half -> EkT fp32 [h4][bt][4] (attn's coalesced layout).
// ---------------------------------------------------------------------------
__global__ __launch_bounds__(256) void proj_mfma_kernel(
    const float* __restrict__ Q, const float* __restrict__ K,
    const float* __restrict__ Wq, const float* __restrict__ Wk,
    float* __restrict__ Eq, float* __restrict__ EkT)
{
    int wid_g = blockIdx.x * 4 + (threadIdx.x >> 6);   // 0..2047
    int lane = threadIdx.x & 63;
    int btile = wid_g >> 4;          // 0..127  (x16 rows)
    int otile = wid_g & 15;          // 0..15   (x16 outs)
    bool isK = (btile >= 64);
    int bt0 = (btile & 63) * 16;
    int o0 = otile * 16;
    const float* X = isK ? K : Q;
    const float* W = isK ? Wk : Wq;

    int rsel = lane & 15;            // row-within-16 for A/B frags
    int ksel = (lane >> 4) * 8;      // k-offset within 32

    const float* xp = X + (bt0 + rsel) * HH + ksel;
    const float* wp = W + (o0 + rsel) * HH + ksel;

    f32x4 acc = {0.f, 0.f, 0.f, 0.f};
#pragma unroll 2
    for (int kb = 0; kb < 8; ++kb) {
        short8 a = load_cvt8(xp + kb * 32);
        short8 b = load_cvt8(wp + kb * 32);
        acc = __builtin_amdgcn_mfma_f32_16x16x32_bf16(a, b, acc, 0, 0, 0);
    }

    int rbase = bt0 + (lane >> 4) * 4;   // C/D row base (bt index)
    int o = o0 + (lane & 15);            // out channel
#pragma unroll
    for (int j = 0; j < 4; ++j) {
        float e = __builtin_amdgcn_exp2f(acc[j] * C2LOG2E);
        int r = rbase + j;
        if (!isK)
            Eq[r * HH + o] = e;
        else
            EkT[((o >> 2) * NBT + r) * 4 + (o & 3)] = e;
    }
}

// ---------------------------------------------------------------------------
// Kernel 2 (attn): unchanged (measured ~5us).
// scores via rcp(Eq*Ek+1) + sum-only softmax + fp32 K context.
// ---------------------------------------------------------------------------
__global__ __launch_bounds__(512, 8) void attn_kernel(
    const float* __restrict__ Eq, const float* __restrict__ EkT,
    const float* __restrict__ Kraw, const float* __restrict__ v,
    float* __restrict__ ctx, float* __restrict__ alpha)
{
    __shared__ float eq_sh[HH];
    __shared__ float v2_sh[HH];
    __shared__ float al_sh[TT];
    __shared__ float red[8];
    __shared__ float4 cred[8][64];

    int bt = blockIdx.x;
    int b = bt / TT;
    int idx = bt % TT;
    int t = (idx < 256) ? idx : 767 - idx;
    int btr = b * TT + t;
    int tid = threadIdx.x;

    if (tid < HH) {
        eq_sh[tid] = Eq[btr * HH + tid];
        v2_sh[tid] = -2.0f * v[tid];
    }
    __syncthreads();

    // ---- score for s = tid (coalesced EkT loads: lanes contiguous) ----
    float sc = 0.f;
    if (tid <= t) {
        const float4* ek = reinterpret_cast<const float4*>(EkT) + (b * TT + tid);
        const float4* q4p = reinterpret_cast<const float4*>(eq_sh);
        const float4* v4p = reinterpret_cast<const float4*>(v2_sh);
#pragma unroll 4
        for (int h4 = 0; h4 < HH / 4; ++h4) {
            float4 e4 = ek[h4 * NBT];     // 1KB/wave
            float4 q4 = q4p[h4];          // broadcast
            float4 vv = v4p[h4];          // broadcast
            float r0 = __builtin_amdgcn_rcpf(__builtin_fmaf(q4.x, e4.x, 1.f));
            float r1 = __builtin_amdgcn_rcpf(__builtin_fmaf(q4.y, e4.y, 1.f));
            float r2 = __builtin_amdgcn_rcpf(__builtin_fmaf(q4.z, e4.z, 1.f));
            float r3 = __builtin_amdgcn_rcpf(__builtin_fmaf(q4.w, e4.w, 1.f));
            sc = __builtin_fmaf(vv.x, r0, sc);
            sc = __builtin_fmaf(vv.y, r1, sc);
            sc = __builtin_fmaf(vv.z, r2, sc);
            sc = __builtin_fmaf(vv.w, r3, sc);
        }
    }

    // ---- softmax: sum only (scores bounded by 2*sum|v| ~ 26) ----
    float e = (tid <= t) ? __builtin_amdgcn_exp2f(sc * LOG2E) : 0.f;
    float ssum = e;
#pragma unroll
    for (int off = 32; off > 0; off >>= 1)
        ssum += __shfl_xor(ssum, off);
    if ((tid & 63) == 0) red[tid >> 6] = ssum;
    __syncthreads();
    float denom = (red[0] + red[1]) + (red[2] + red[3])
                + (red[4] + red[5]) + (red[6] + red[7]);
    float a0 = e * __builtin_amdgcn_rcpf(denom);

    al_sh[tid] = a0;
    alpha[btr * TT + tid] = a0;
    __syncthreads();

    // ---- context: hc = tid&63 (4 channels), sg = tid>>6 (s-stride 8) ----
    int hc = tid & 63, sg = tid >> 6;
    const float4* kb4 = reinterpret_cast<const float4*>(Kraw + b * TT * HH) + hc;
    float4 acc4 = {0.f, 0.f, 0.f, 0.f};
    for (int s = sg; s <= t; s += 8) {
        float4 k4 = kb4[s * 64];             // coalesced 1KB/wave
        float  al = al_sh[s];                // wave-uniform broadcast
        acc4.x = __builtin_fmaf(al, k4.x, acc4.x);
        acc4.y = __builtin_fmaf(al, k4.y, acc4.y);
        acc4.z = __builtin_fmaf(al, k4.z, acc4.z);
        acc4.w = __builtin_fmaf(al, k4.w, acc4.w);
    }
    cred[sg][hc] = acc4;
    __syncthreads();
    if (sg == 0) {
        float4 out = {0.f, 0.f, 0.f, 0.f};
#pragma unroll
        for (int g = 0; g < 8; ++g) {
            float4 cc = cred[g][hc];
            out.x += cc.x; out.y += cc.y; out.z += cc.z; out.w += cc.w;
        }
        reinterpret_cast<float4*>(ctx + btr * HH)[hc] = out;
    }
}

extern "C" void kernel_launch(void* const* d_in, const int* in_sizes, int n_in,
                              void* d_out, int out_size, void* d_ws, size_t ws_size,
                              hipStream_t stream) {
    const float* Q  = (const float*)d_in[0];
    const float* K  = (const float*)d_in[1];
    const float* Wq = (const float*)d_in[2];
    const float* Wk = (const float*)d_in[3];
    const float* v  = (const float*)d_in[4];

    float* ctx   = (float*)d_out;                      // B*T*H
    float* alpha = (float*)d_out + NBT * HH;           // B*T*T

    // ws: Eq fp32 | EkT fp32
    float* Eq  = (float*)d_ws;                         // NBT*HH fp32 (1 MB)
    float* EkT = Eq + NBT * HH;                        // NBT*HH fp32 (1 MB)

    proj_mfma_kernel<<<512, 256, 0, stream>>>(Q, K, Wq, Wk, Eq, EkT);
    attn_kernel<<<NBT, 512, 0, stream>>>(Eq, EkT, K, v, ctx, alpha);
}